// Round 5
// baseline (259.883 us; speedup 1.0000x reference)
//
#include <hip/hip_runtime.h>

#define K_DIM 8192
#define M_REAL 2000
#define N_REAL 2000
#define M_PAD 2048
#define N_PAD 2048

#define BM 256
#define BN 256
#define BK 32
#define SPLITK 4
#define KSLAB (K_DIM / SPLITK)   // 2048
#define NSTEP (KSLAB / BK)       // 64 K-steps per block

// fused prep block ranges
#define NB_W 1024
#define NB_X 2048
#define NB_I 256

typedef __bf16 bf16x8 __attribute__((ext_vector_type(8)));
typedef float f32x4 __attribute__((ext_vector_type(4)));
typedef float fvec4 __attribute__((ext_vector_type(4)));

#define RAW_BARRIER()  asm volatile("s_barrier" ::: "memory")
#define WAIT_VM8()     asm volatile("s_waitcnt vmcnt(8)" ::: "memory")
#define WAIT_VM4()     asm volatile("s_waitcnt vmcnt(4)" ::: "memory")
#define WAIT_VM0()     asm volatile("s_waitcnt vmcnt(0)" ::: "memory")

__device__ __forceinline__ unsigned short f2bf(float f) {
    union { float f; unsigned u; } v; v.f = f;
    unsigned r = v.u + 0x7FFFu + ((v.u >> 16) & 1u);  // RNE; inputs are finite normals
    return (unsigned short)(r >> 16);
}

__device__ __forceinline__ unsigned pk2(float a, float b) {
    return (unsigned)f2bf(a) | ((unsigned)f2bf(b) << 16);
}

__device__ __forceinline__ void async16(const void* g, void* l) {
    __builtin_amdgcn_global_load_lds((__attribute__((address_space(1))) void*)(g),
                                     (__attribute__((address_space(3))) void*)(l),
                                     16, 0, 0);
}

// ---------------------------------------------------------------------------
// Fused prep (one dispatch) — UNCHANGED from R4:
//   blocks [0,1024):       W f32 -> Wb bf16 [2048][8192], grid-stride, 32B ld/16B st
//   blocks [1024,3072):    X [8192][2000] f32 -> XT bf16 [2048][8192] transpose,
//                          conflict-free LDS (row stride 65 words === 1 mod 32)
//   blocks [3072,3328):    out[m][n] = bias[n] (float4 stores, grid-stride)
__global__ __launch_bounds__(256) void prep_kernel(const float* __restrict__ W,
                                                   const float* __restrict__ X,
                                                   const float* __restrict__ bias,
                                                   unsigned short* __restrict__ Wb,
                                                   unsigned short* __restrict__ XT,
                                                   float* __restrict__ out) {
    __shared__ unsigned short T[64][130];
    int bid = blockIdx.x;
    if (bid < NB_W) {
        unsigned tid = bid * 256u + threadIdx.x;
#pragma unroll
        for (unsigned i = 0; i < 8; ++i) {
            unsigned e = (i * (1024u * 256u) + tid) * 8u;       // element index
            uint4 o = make_uint4(0u, 0u, 0u, 0u);
            if (e < (unsigned)(M_REAL * K_DIM)) {
                fvec4 f0 = __builtin_nontemporal_load((const fvec4*)(W + e));
                fvec4 f1 = __builtin_nontemporal_load((const fvec4*)(W + e + 4));
                o.x = pk2(f0.x, f0.y);
                o.y = pk2(f0.z, f0.w);
                o.z = pk2(f1.x, f1.y);
                o.w = pk2(f1.z, f1.w);
            }
            *(uint4*)(Wb + e) = o;
        }
    } else if (bid < NB_W + NB_X) {
        int b = bid - NB_W;
        int k0 = (b & 63) << 7;        // 0..8064 step 128
        int n0 = (b >> 6) << 6;        // 0..1984 step 64
        int t = threadIdx.x;
        int c = t & 15;
        int r = t >> 4;
        int nl = c << 2;               // local n base (x4)
        int n = n0 + nl;
        bool valid = (n < N_REAL);
#pragma unroll
        for (int p = 0; p < 4; ++p) {
            int kl = (r << 1) + (p << 5);
            fvec4 v0 = {0.f, 0.f, 0.f, 0.f};
            fvec4 v1 = {0.f, 0.f, 0.f, 0.f};
            if (valid) {
                v0 = __builtin_nontemporal_load((const fvec4*)(X + (k0 + kl) * N_REAL + n));
                v1 = __builtin_nontemporal_load((const fvec4*)(X + (k0 + kl + 1) * N_REAL + n));
            }
            *(unsigned*)&T[nl + 0][kl] = pk2(v0.x, v1.x);
            *(unsigned*)&T[nl + 1][kl] = pk2(v0.y, v1.y);
            *(unsigned*)&T[nl + 2][kl] = pk2(v0.z, v1.z);
            *(unsigned*)&T[nl + 3][kl] = pk2(v0.w, v1.w);
        }
        __syncthreads();
#pragma unroll
        for (int it = 0; it < 4; ++it) {
            int nl2 = r + (it << 4);
            int kl2 = c << 3;
            const unsigned* tp = (const unsigned*)&T[nl2][kl2];
            uint4 o;
            o.x = tp[0]; o.y = tp[1]; o.z = tp[2]; o.w = tp[3];
            *(uint4*)(XT + (((n0 + nl2) << 13) + k0 + kl2)) = o;
        }
    } else {
        const int total = M_REAL * (N_REAL / 4);   // 1,000,000 float4
        for (int i = (bid - NB_W - NB_X) * 256 + (int)threadIdx.x; i < total; i += NB_I * 256) {
            int m = i / (N_REAL / 4);
            int n4 = i - m * (N_REAL / 4);
            float4 bv = *(const float4*)(bias + (n4 << 2));
            *(float4*)(out + m * N_REAL + (n4 << 2)) = bv;
        }
    }
}

// ---------------------------------------------------------------------------
// Split-K GEMM, 256x256 tile, BK=32, 4-deep LDS pipeline (128 KiB).
//
// R5 change: 4 barriers/step -> ONE barrier/step. Dependence analysis of the
// 4-deep ring: the buffer STAGEd at step s ((s+3)&3) was last read at step
// s-1, and the buffer read at step s+1 is vmcnt-landed before the end of
// step s -- so the single end-of-step barrier (placed after the counted
// WAIT_VM8) simultaneously (a) publishes buffer s+1 to all waves and (b)
// proves all waves finished step s's ds_reads before step s+1's STAGE
// rewrites buffer s&3. The mid-step barriers protected nothing.
// ds_reads are plain C++ -> compiler emits fine-grained lgkmcnt and
// interleaves reads with MFMAs; waves slide within a step -> cross-wave
// MFMA || LDS || VMEM overlap (the m97/m114 implicit-overlap mechanism),
// while keeping counted vmcnt (T4), zero-conflict swizzle (T2), setprio (T5).
//
// T2 swizzle: chunk ^= (row>>1)&3 -- (row&1, chunk) bijective per 8-row
// group -> 8 slots, 2-way = free [R4-verified: SQ_LDS_BANK_CONFLICT == 0].
// Applied both sides (rule #21): pre-swizzled global source + reader XOR.
__global__ __launch_bounds__(512, 2) void gemm_kernel(const unsigned short* __restrict__ Wb,
                                                      const unsigned short* __restrict__ XT,
                                                      float* __restrict__ out) {
    __shared__ __align__(16) unsigned short As[4][BM * BK];  // 4 x 16 KB
    __shared__ __align__(16) unsigned short Bs[4][BN * BK];  // 4 x 16 KB

    int f = blockIdx.x;
    int xcd = f & 7;
    int local = f >> 3;                    // 0..31
    int bz = local & 3;
    int bx = (xcd & 3) * 2 + ((local >> 2) & 1);   // 0..7
    int by = (xcd >> 2) * 4 + (local >> 3);        // 0..7

    int t = threadIdx.x;
    int w = t >> 6;              // 0..7
    int l = t & 63;
    int wm = (w >> 2) * 128;     // 0 or 128
    int wn = (w & 3) * 64;       // 0,64,128,192
    int lane16 = l & 15;
    int quad = l >> 4;
    int m0 = by * BM;
    int n0 = bx * BN;
    int ks = bz * KSLAB;

    f32x4 acc[8][4] = {};

    // ---- staging source pointers (pre-swizzled chunk within each 64B row) ----
    int rlin = t >> 2;                       // 0..127 (round-0 row; round1 = +128)
    int ck = (t & 3) ^ ((rlin >> 1) & 3);    // 16B chunk index, swizzled (T2)
    const unsigned short* gA0 = Wb + (long long)(m0 + rlin) * K_DIM + ks + ck * 8;
    const unsigned short* gA1 = gA0 + 128LL * K_DIM;
    const unsigned short* gB0 = XT + (long long)(n0 + rlin) * K_DIM + ks + ck * 8;
    const unsigned short* gB1 = gB0 + 128LL * K_DIM;

    char* smA = (char*)&As[0][0];
    char* smB = (char*)&Bs[0][0];
    int wslot = w * 1024;                    // wave-uniform LDS slot within a round

#define STAGE_A(OFF) do { \
        async16(gA0, smA + (OFF) + wslot); \
        async16(gA1, smA + (OFF) + 8192 + wslot); \
        gA0 += BK; gA1 += BK; } while (0)
#define STAGE_B(OFF) do { \
        async16(gB0, smB + (OFF) + wslot); \
        async16(gB1, smB + (OFF) + 8192 + wslot); \
        gB0 += BK; gB1 += BK; } while (0)

    // ---- reader-side swizzled row offsets (bytes within one 16 KB buffer) ----
    // row mod 8 == lane16 mod 8 for every frag (frag strides are 16 rows).
    int swz = ((quad ^ ((lane16 >> 1) & 3)) << 4);   // 16B chunk swizzle (T2)
    int arow = (wm + lane16) * 64 + swz;
    int brow = (wn + lane16) * 64 + swz;

    // ---- prologue: stage K-steps 0,1,2 (12 loads), wait for step 0 ----
    STAGE_A(0);     STAGE_B(0);
    STAGE_A(16384); STAGE_B(16384);
    STAGE_A(32768); STAGE_B(32768);
    WAIT_VM8();                      // 8 newest = steps 1,2 -> step 0 landed
    RAW_BARRIER();

    int cur = 0;
    int stg = 49152;

    bf16x8 a0, a1, a2, a3, b0, b1, b2, b3;

    for (int s = 0; s < NSTEP; ++s) {
        const char* ab = smA + cur + arow;
        const char* bb = smB + cur + brow;
        // frag reads (plain C++ -> compiler-scheduled fine-grained lgkmcnt)
        a0 = *(const bf16x8*)(ab);
        a1 = *(const bf16x8*)(ab + 1024);
        a2 = *(const bf16x8*)(ab + 2048);
        a3 = *(const bf16x8*)(ab + 3072);
        b0 = *(const bf16x8*)(bb);
        b1 = *(const bf16x8*)(bb + 1024);
        b2 = *(const bf16x8*)(bb + 2048);
        b3 = *(const bf16x8*)(bb + 3072);

        if (s < NSTEP - 3) {                 // stage step s+3
            STAGE_A(stg);
            STAGE_B(stg);
        }

        __builtin_amdgcn_s_setprio(1);
        acc[0][0] = __builtin_amdgcn_mfma_f32_16x16x32_bf16(a0, b0, acc[0][0], 0, 0, 0);
        acc[0][1] = __builtin_amdgcn_mfma_f32_16x16x32_bf16(a0, b1, acc[0][1], 0, 0, 0);
        acc[0][2] = __builtin_amdgcn_mfma_f32_16x16x32_bf16(a0, b2, acc[0][2], 0, 0, 0);
        acc[0][3] = __builtin_amdgcn_mfma_f32_16x16x32_bf16(a0, b3, acc[0][3], 0, 0, 0);
        acc[1][0] = __builtin_amdgcn_mfma_f32_16x16x32_bf16(a1, b0, acc[1][0], 0, 0, 0);
        acc[1][1] = __builtin_amdgcn_mfma_f32_16x16x32_bf16(a1, b1, acc[1][1], 0, 0, 0);
        acc[1][2] = __builtin_amdgcn_mfma_f32_16x16x32_bf16(a1, b2, acc[1][2], 0, 0, 0);
        acc[1][3] = __builtin_amdgcn_mfma_f32_16x16x32_bf16(a1, b3, acc[1][3], 0, 0, 0);
        acc[2][0] = __builtin_amdgcn_mfma_f32_16x16x32_bf16(a2, b0, acc[2][0], 0, 0, 0);
        acc[2][1] = __builtin_amdgcn_mfma_f32_16x16x32_bf16(a2, b1, acc[2][1], 0, 0, 0);
        acc[2][2] = __builtin_amdgcn_mfma_f32_16x16x32_bf16(a2, b2, acc[2][2], 0, 0, 0);
        acc[2][3] = __builtin_amdgcn_mfma_f32_16x16x32_bf16(a2, b3, acc[2][3], 0, 0, 0);
        acc[3][0] = __builtin_amdgcn_mfma_f32_16x16x32_bf16(a3, b0, acc[3][0], 0, 0, 0);
        acc[3][1] = __builtin_amdgcn_mfma_f32_16x16x32_bf16(a3, b1, acc[3][1], 0, 0, 0);
        acc[3][2] = __builtin_amdgcn_mfma_f32_16x16x32_bf16(a3, b2, acc[3][2], 0, 0, 0);
        acc[3][3] = __builtin_amdgcn_mfma_f32_16x16x32_bf16(a3, b3, acc[3][3], 0, 0, 0);
        __builtin_amdgcn_s_setprio(0);

        // second-half A frags (same cur buffer -- stays valid all step)
        a0 = *(const bf16x8*)(ab + 4096);
        a1 = *(const bf16x8*)(ab + 5120);
        a2 = *(const bf16x8*)(ab + 6144);
        a3 = *(const bf16x8*)(ab + 7168);

        __builtin_amdgcn_s_setprio(1);
        acc[4][0] = __builtin_amdgcn_mfma_f32_16x16x32_bf16(a0, b0, acc[4][0], 0, 0, 0);
        acc[4][1] = __builtin_amdgcn_mfma_f32_16x16x32_bf16(a0, b1, acc[4][1], 0, 0, 0);
        acc[4][2] = __builtin_amdgcn_mfma_f32_16x16x32_bf16(a0, b2, acc[4][2], 0, 0, 0);
        acc[4][3] = __builtin_amdgcn_mfma_f32_16x16x32_bf16(a0, b3, acc[4][3], 0, 0, 0);
        acc[5][0] = __builtin_amdgcn_mfma_f32_16x16x32_bf16(a1, b0, acc[5][0], 0, 0, 0);
        acc[5][1] = __builtin_amdgcn_mfma_f32_16x16x32_bf16(a1, b1, acc[5][1], 0, 0, 0);
        acc[5][2] = __builtin_amdgcn_mfma_f32_16x16x32_bf16(a1, b2, acc[5][2], 0, 0, 0);
        acc[5][3] = __builtin_amdgcn_mfma_f32_16x16x32_bf16(a1, b3, acc[5][3], 0, 0, 0);
        acc[6][0] = __builtin_amdgcn_mfma_f32_16x16x32_bf16(a2, b0, acc[6][0], 0, 0, 0);
        acc[6][1] = __builtin_amdgcn_mfma_f32_16x16x32_bf16(a2, b1, acc[6][1], 0, 0, 0);
        acc[6][2] = __builtin_amdgcn_mfma_f32_16x16x32_bf16(a2, b2, acc[6][2], 0, 0, 0);
        acc[6][3] = __builtin_amdgcn_mfma_f32_16x16x32_bf16(a2, b3, acc[6][3], 0, 0, 0);
        acc[7][0] = __builtin_amdgcn_mfma_f32_16x16x32_bf16(a3, b0, acc[7][0], 0, 0, 0);
        acc[7][1] = __builtin_amdgcn_mfma_f32_16x16x32_bf16(a3, b1, acc[7][1], 0, 0, 0);
        acc[7][2] = __builtin_amdgcn_mfma_f32_16x16x32_bf16(a3, b2, acc[7][2], 0, 0, 0);
        acc[7][3] = __builtin_amdgcn_mfma_f32_16x16x32_bf16(a3, b3, acc[7][3], 0, 0, 0);
        __builtin_amdgcn_s_setprio(0);

        // single end-of-step sync: counted vmcnt + barrier
        if (s < NSTEP - 3) {
            WAIT_VM8();              // 8 newest = steps s+2,s+3 -> s+1 landed
        } else if (s == NSTEP - 3) {
            WAIT_VM4();              // 4 newest = step 63 -> step 62 landed
        } else if (s == NSTEP - 2) {
            WAIT_VM0();              // step 63 landed
        }
        if (s < NSTEP - 1)
            RAW_BARRIER();

        cur = (cur + 16384) & 65535;
        stg = (stg + 16384) & 65535;
    }
#undef STAGE_A
#undef STAGE_B

    // Epilogue: C/D layout col = lane&15, row = quad*4 + reg  [m89-verified]
#pragma unroll
    for (int j = 0; j < 4; ++j) {
        int n = n0 + wn + j * 16 + lane16;
        if (n >= N_REAL) continue;
#pragma unroll
        for (int i = 0; i < 8; ++i) {
            int mbase = m0 + wm + i * 16 + quad * 4;
#pragma unroll
            for (int r = 0; r < 4; ++r) {
                int m = mbase + r;
                if (m < M_REAL)
                    atomicAdd(&out[(long long)m * N_REAL + n], acc[i][j][r]);
            }
        }
    }
}

// ---------------------------------------------------------------------------
extern "C" void kernel_launch(void* const* d_in, const int* in_sizes, int n_in,
                              void* d_out, int out_size, void* d_ws, size_t ws_size,
                              hipStream_t stream) {
    const float* W    = (const float*)d_in[0];  // [2000][8192]
    const float* bias = (const float*)d_in[1];  // [2000]
    const float* X    = (const float*)d_in[2];  // [8192][2000]
    float* out = (float*)d_out;

    unsigned short* Wb = (unsigned short*)d_ws;                 // [2048][8192] bf16
    unsigned short* XT = Wb + (long long)M_PAD * K_DIM;         // [2048][8192] bf16

    prep_kernel<<<NB_W + NB_X + NB_I, 256, 0, stream>>>(W, X, bias, Wb, XT, out);

    gemm_kernel<<<(N_PAD / BN) * (M_PAD / BM) * SPLITK, 512, 0, stream>>>(Wb, XT, out);
}

// Round 6
// 259.040 us; speedup vs baseline: 1.0033x; 1.0033x over previous
//
#include <hip/hip_runtime.h>

#define K_DIM 8192
#define M_REAL 2000
#define N_REAL 2000
#define M_PAD 2048
#define N_PAD 2048

#define BM 128
#define BN 128
#define BK 32
#define SPLITK 4
#define KSLAB (K_DIM / SPLITK)   // 2048
#define NSTEP (KSLAB / BK)       // 64 K-steps per block

// fused prep block ranges
#define NB_W 1024
#define NB_X 2048
#define NB_I 256

typedef __bf16 bf16x8 __attribute__((ext_vector_type(8)));
typedef float f32x4 __attribute__((ext_vector_type(4)));
typedef float fvec4 __attribute__((ext_vector_type(4)));

__device__ __forceinline__ unsigned short f2bf(float f) {
    union { float f; unsigned u; } v; v.f = f;
    unsigned r = v.u + 0x7FFFu + ((v.u >> 16) & 1u);  // RNE; inputs are finite normals
    return (unsigned short)(r >> 16);
}

__device__ __forceinline__ unsigned pk2(float a, float b) {
    return (unsigned)f2bf(a) | ((unsigned)f2bf(b) << 16);
}

__device__ __forceinline__ void async16(const void* g, void* l) {
    __builtin_amdgcn_global_load_lds((__attribute__((address_space(1))) void*)(g),
                                     (__attribute__((address_space(3))) void*)(l),
                                     16, 0, 0);
}

// ---------------------------------------------------------------------------
// Fused prep (one dispatch) — UNCHANGED (measured near-roofline ~45 us for
// 212 MB):
//   blocks [0,1024):       W f32 -> Wb bf16 [2048][8192], grid-stride, 32B ld/16B st
//   blocks [1024,3072):    X [8192][2000] f32 -> XT bf16 [2048][8192] transpose,
//                          conflict-free LDS (row stride 65 words === 1 mod 32)
//   blocks [3072,3328):    out[m][n] = bias[n] (float4 stores, grid-stride)
__global__ __launch_bounds__(256) void prep_kernel(const float* __restrict__ W,
                                                   const float* __restrict__ X,
                                                   const float* __restrict__ bias,
                                                   unsigned short* __restrict__ Wb,
                                                   unsigned short* __restrict__ XT,
                                                   float* __restrict__ out) {
    __shared__ unsigned short T[64][130];
    int bid = blockIdx.x;
    if (bid < NB_W) {
        unsigned tid = bid * 256u + threadIdx.x;
#pragma unroll
        for (unsigned i = 0; i < 8; ++i) {
            unsigned e = (i * (1024u * 256u) + tid) * 8u;       // element index
            uint4 o = make_uint4(0u, 0u, 0u, 0u);
            if (e < (unsigned)(M_REAL * K_DIM)) {
                fvec4 f0 = __builtin_nontemporal_load((const fvec4*)(W + e));
                fvec4 f1 = __builtin_nontemporal_load((const fvec4*)(W + e + 4));
                o.x = pk2(f0.x, f0.y);
                o.y = pk2(f0.z, f0.w);
                o.z = pk2(f1.x, f1.y);
                o.w = pk2(f1.z, f1.w);
            }
            *(uint4*)(Wb + e) = o;
        }
    } else if (bid < NB_W + NB_X) {
        int b = bid - NB_W;
        int k0 = (b & 63) << 7;        // 0..8064 step 128
        int n0 = (b >> 6) << 6;        // 0..1984 step 64
        int t = threadIdx.x;
        int c = t & 15;
        int r = t >> 4;
        int nl = c << 2;               // local n base (x4)
        int n = n0 + nl;
        bool valid = (n < N_REAL);
#pragma unroll
        for (int p = 0; p < 4; ++p) {
            int kl = (r << 1) + (p << 5);
            fvec4 v0 = {0.f, 0.f, 0.f, 0.f};
            fvec4 v1 = {0.f, 0.f, 0.f, 0.f};
            if (valid) {
                v0 = __builtin_nontemporal_load((const fvec4*)(X + (k0 + kl) * N_REAL + n));
                v1 = __builtin_nontemporal_load((const fvec4*)(X + (k0 + kl + 1) * N_REAL + n));
            }
            *(unsigned*)&T[nl + 0][kl] = pk2(v0.x, v1.x);
            *(unsigned*)&T[nl + 1][kl] = pk2(v0.y, v1.y);
            *(unsigned*)&T[nl + 2][kl] = pk2(v0.z, v1.z);
            *(unsigned*)&T[nl + 3][kl] = pk2(v0.w, v1.w);
        }
        __syncthreads();
#pragma unroll
        for (int it = 0; it < 4; ++it) {
            int nl2 = r + (it << 4);
            int kl2 = c << 3;
            const unsigned* tp = (const unsigned*)&T[nl2][kl2];
            uint4 o;
            o.x = tp[0]; o.y = tp[1]; o.z = tp[2]; o.w = tp[3];
            *(uint4*)(XT + (((n0 + nl2) << 13) + k0 + kl2)) = o;
        }
    } else {
        const int total = M_REAL * (N_REAL / 4);   // 1,000,000 float4
        for (int i = (bid - NB_W - NB_X) * 256 + (int)threadIdx.x; i < total; i += NB_I * 256) {
            int m = i / (N_REAL / 4);
            int n4 = i - m * (N_REAL / 4);
            float4 bv = *(const float4*)(bias + (n4 << 2));
            *(float4*)(out + m * N_REAL + (n4 << 2)) = bv;
        }
    }
}

// ---------------------------------------------------------------------------
// R6: occupancy-first GEMM (m97 structure, measured 912 TF at 128^2):
//   128x128 tile, BK=32, 256 threads (4 waves, 64x64 wave-tiles, 4x4 frags),
//   2-deep LDS (32 KiB/block -> 4 blocks/CU with SPLITK=4 grid of 1024),
//   16 waves/CU = 4 waves/SIMD -> TLP provides the MFMA||LDS||VMEM overlap
//   (m114 mechanism) that barrier-scheduling failed to create at 2 waves/SIMD
//   (R2/R4/R5 all 112-115 us). Plain stage -> compute -> __syncthreads loop;
//   the vmcnt drain at the barrier is covered by the other 3 blocks on the CU.
//
// T2 swizzle (R4-verified zero conflicts, identical 64B-row geometry):
//   phys_chunk = log_chunk ^ ((row>>1)&3); row&1 feeds bank bit 4
//   (64B rows -> row*16 mod 32) -> uniform 8 lanes per bank-quad = even port
//   utilization. Applied both sides (rule #21): pre-swizzled global source
//   for global_load_lds (linear dest) + same XOR on the ds_read address.
__global__ __launch_bounds__(256, 4) void gemm_kernel(const unsigned short* __restrict__ Wb,
                                                      const unsigned short* __restrict__ XT,
                                                      float* __restrict__ out) {
    __shared__ __align__(16) char smA[2 * 8192];   // A: 2 x (128 rows x 64 B)
    __shared__ __align__(16) char smB[2 * 8192];   // B: 2 x (128 rows x 64 B)

    int f = blockIdx.x;
    int xcd = f & 7;
    int local = f >> 3;            // 0..127
    int bz = local & 3;
    int lt = local >> 2;           // 0..31
    int bx = (xcd & 3) * 4 + (lt & 3);     // 0..15
    int by = (xcd >> 2) * 8 + (lt >> 2);   // 0..15

    int t = threadIdx.x;
    int w = t >> 6;                // 0..3
    int l = t & 63;
    int lane16 = l & 15;
    int quad = l >> 4;
    int wr = w >> 1;               // 0..1  (m-half)
    int wc = w & 1;                // 0..1  (n-half)
    int m0 = by * BM;
    int n0 = bx * BN;
    int ks = bz * KSLAB;

    f32x4 acc[4][4] = {};

    // ---- staging map: wave w covers rows w*32..w*32+31 (2 calls x 16 rows);
    //      lane l -> row w*32 + c*16 + (l>>2), phys chunk l&3.
    //      Pre-swizzled source logical chunk: (l&3) ^ ((row>>1)&3) with
    //      (row>>1)&3 == (l>>3)&3 for both calls.
    int rowS = w * 32 + (l >> 2);
    int lc   = (l & 3) ^ ((l >> 3) & 3);
    const unsigned short* gA0 = Wb + (long long)(m0 + rowS) * K_DIM + ks + lc * 8;
    const unsigned short* gA1 = gA0 + 16LL * K_DIM;
    const unsigned short* gB0 = XT + (long long)(n0 + rowS) * K_DIM + ks + lc * 8;
    const unsigned short* gB1 = gB0 + 16LL * K_DIM;

#define STAGE(BUF, KOFF) do { \
        int bo_ = (BUF) * 8192 + w * 2048; \
        async16(gA0 + (KOFF), smA + bo_); \
        async16(gA1 + (KOFF), smA + bo_ + 1024); \
        async16(gB0 + (KOFF), smB + bo_); \
        async16(gB1 + (KOFF), smB + bo_ + 1024); \
    } while (0)

    // ---- reader-side swizzled row offsets (bytes within one 8 KB buffer) ----
    int swz = ((quad ^ ((lane16 >> 1) & 3)) << 4);
    int arow = (wr * 64 + lane16) * 64 + swz;
    int brow = (wc * 64 + lane16) * 64 + swz;

    // ---- prologue ----
    STAGE(0, 0);
    __syncthreads();

    for (int s = 0; s < NSTEP; ++s) {
        if (s + 1 < NSTEP)
            STAGE((s + 1) & 1, (s + 1) * BK);

        int bo = (s & 1) * 8192;
        const char* Ab = smA + bo + arow;
        const char* Bb = smB + bo + brow;
        bf16x8 a0 = *(const bf16x8*)(Ab);
        bf16x8 a1 = *(const bf16x8*)(Ab + 1024);
        bf16x8 a2 = *(const bf16x8*)(Ab + 2048);
        bf16x8 a3 = *(const bf16x8*)(Ab + 3072);
        bf16x8 b0 = *(const bf16x8*)(Bb);
        bf16x8 b1 = *(const bf16x8*)(Bb + 1024);
        bf16x8 b2 = *(const bf16x8*)(Bb + 2048);
        bf16x8 b3 = *(const bf16x8*)(Bb + 3072);

        acc[0][0] = __builtin_amdgcn_mfma_f32_16x16x32_bf16(a0, b0, acc[0][0], 0, 0, 0);
        acc[0][1] = __builtin_amdgcn_mfma_f32_16x16x32_bf16(a0, b1, acc[0][1], 0, 0, 0);
        acc[0][2] = __builtin_amdgcn_mfma_f32_16x16x32_bf16(a0, b2, acc[0][2], 0, 0, 0);
        acc[0][3] = __builtin_amdgcn_mfma_f32_16x16x32_bf16(a0, b3, acc[0][3], 0, 0, 0);
        acc[1][0] = __builtin_amdgcn_mfma_f32_16x16x32_bf16(a1, b0, acc[1][0], 0, 0, 0);
        acc[1][1] = __builtin_amdgcn_mfma_f32_16x16x32_bf16(a1, b1, acc[1][1], 0, 0, 0);
        acc[1][2] = __builtin_amdgcn_mfma_f32_16x16x32_bf16(a1, b2, acc[1][2], 0, 0, 0);
        acc[1][3] = __builtin_amdgcn_mfma_f32_16x16x32_bf16(a1, b3, acc[1][3], 0, 0, 0);
        acc[2][0] = __builtin_amdgcn_mfma_f32_16x16x32_bf16(a2, b0, acc[2][0], 0, 0, 0);
        acc[2][1] = __builtin_amdgcn_mfma_f32_16x16x32_bf16(a2, b1, acc[2][1], 0, 0, 0);
        acc[2][2] = __builtin_amdgcn_mfma_f32_16x16x32_bf16(a2, b2, acc[2][2], 0, 0, 0);
        acc[2][3] = __builtin_amdgcn_mfma_f32_16x16x32_bf16(a2, b3, acc[2][3], 0, 0, 0);
        acc[3][0] = __builtin_amdgcn_mfma_f32_16x16x32_bf16(a3, b0, acc[3][0], 0, 0, 0);
        acc[3][1] = __builtin_amdgcn_mfma_f32_16x16x32_bf16(a3, b1, acc[3][1], 0, 0, 0);
        acc[3][2] = __builtin_amdgcn_mfma_f32_16x16x32_bf16(a3, b2, acc[3][2], 0, 0, 0);
        acc[3][3] = __builtin_amdgcn_mfma_f32_16x16x32_bf16(a3, b3, acc[3][3], 0, 0, 0);

        if (s + 1 < NSTEP)
            __syncthreads();       // drains vmcnt/lgkm + barrier (m97 semantics)
    }
#undef STAGE

    // Epilogue: C/D layout col = lane&15, row = quad*4 + reg  [m89-verified]
#pragma unroll
    for (int j = 0; j < 4; ++j) {
        int n = n0 + wc * 64 + j * 16 + lane16;
        if (n >= N_REAL) continue;
#pragma unroll
        for (int i = 0; i < 4; ++i) {
            int mbase = m0 + wr * 64 + i * 16 + quad * 4;
#pragma unroll
            for (int r = 0; r < 4; ++r) {
                int m = mbase + r;
                if (m < M_REAL)
                    atomicAdd(&out[(long long)m * N_REAL + n], acc[i][j][r]);
            }
        }
    }
}

// ---------------------------------------------------------------------------
extern "C" void kernel_launch(void* const* d_in, const int* in_sizes, int n_in,
                              void* d_out, int out_size, void* d_ws, size_t ws_size,
                              hipStream_t stream) {
    const float* W    = (const float*)d_in[0];  // [2000][8192]
    const float* bias = (const float*)d_in[1];  // [2000]
    const float* X    = (const float*)d_in[2];  // [8192][2000]
    float* out = (float*)d_out;

    unsigned short* Wb = (unsigned short*)d_ws;                 // [2048][8192] bf16
    unsigned short* XT = Wb + (long long)M_PAD * K_DIM;         // [2048][8192] bf16

    prep_kernel<<<NB_W + NB_X + NB_I, 256, 0, stream>>>(W, X, bias, Wb, XT, out);

    gemm_kernel<<<(N_PAD / BN) * (M_PAD / BM) * SPLITK, 256, 0, stream>>>(Wb, XT, out);
}